// Round 11
// baseline (706.926 us; speedup 1.0000x reference)
//
#include <hip/hip_runtime.h>
#include <math.h>

// ---- weight buffer layout ----
// fp32 section (dwords 0..1232):
// W1[16][5]@0 b1@80 | W2[32][16]@96 b2@608 | W3[16][35]@640 b3@1200 | W4[16]@1216 b4@1232
// packed fp16 section (uint view at dword offset 1280):
// w1p0[16]@0 (k0,k1) | w1p1[16]@16 (k2,k3) | w1p2[16]@32 (k4,0)
// w2pk[32][8]@48 (k2j,k2j+1) | b1p[16]@304 (b,0) | b2p[32]@320 (b,0)  -- 352 dwords
#define WTOT  1233
#define PKOFS 1280
#define PKTOT 352

typedef __fp16 h2 __attribute__((ext_vector_type(2)));

__device__ __forceinline__ h2 u2h(unsigned int u) { return __builtin_bit_cast(h2, u); }
__device__ __forceinline__ unsigned int h2u(h2 h) { return __builtin_bit_cast(unsigned int, h); }
__device__ __forceinline__ unsigned int umax2(unsigned int a, unsigned int b) {
  return h2u(__builtin_elementwise_max(u2h(a), u2h(b)));
}
__device__ __forceinline__ h2 pkfma(h2 a, h2 b, h2 c) {
  return __builtin_elementwise_fma(a, b, c);
}
// horizontal sum: returns dword whose LOW half = a.x + a.y (fp16)
__device__ __forceinline__ unsigned int hsum(h2 a) {
  unsigned int u = h2u(a);
  unsigned int r = __builtin_amdgcn_alignbit(u, u, 16);
  return h2u(a + u2h(r));
}
// combine low halves: D = low16(lo) | low16(hi)<<16
__device__ __forceinline__ unsigned int combo(unsigned int hi, unsigned int lo) {
  return __builtin_amdgcn_perm(hi, lo, 0x05040100u);
}

__device__ __forceinline__ float softplus_f(float x) {
  return fmaxf(x, 0.f) + log1pf(expf(-fabsf(x)));
}

struct PrepArgs {
  const float* wmu[4]; const float* wrho[4]; const float* epsw[4];
  const float* bmu[4]; const float* brho[4]; const float* epsb[4];
  float* out;
};

// single block 1024: sample all weights, then pack fp16 section
__global__ void prep_all_kernel(PrepArgs a) {
  const int wsz[4] = {80, 512, 560, 16};
  const int wof[4] = {0, 96, 640, 1216};
  const int bsz[4] = {16, 32, 16, 1};
  const int bof[4] = {80, 608, 1200, 1232};
  float* wg = a.out;
  int tid = threadIdx.x;
#pragma unroll
  for (int l = 0; l < 4; l++) {
    for (int i = tid; i < wsz[l]; i += 1024)
      wg[wof[l] + i] = a.wmu[l][i] + softplus_f(a.wrho[l][i]) * a.epsw[l][i];
    for (int i = tid; i < bsz[l]; i += 1024)
      wg[bof[l] + i] = a.bmu[l][i] + softplus_f(a.brho[l][i]) * a.epsb[l][i];
  }
  __syncthreads();
  unsigned int* wp = (unsigned int*)(wg + PKOFS);
  int t = tid;
  if (t < 16) {
    wp[t]       = h2u(__builtin_amdgcn_cvt_pkrtz(wg[t * 5 + 0], wg[t * 5 + 1]));
    wp[16 + t]  = h2u(__builtin_amdgcn_cvt_pkrtz(wg[t * 5 + 2], wg[t * 5 + 3]));
    wp[32 + t]  = h2u(__builtin_amdgcn_cvt_pkrtz(wg[t * 5 + 4], 0.f));
    wp[304 + t] = h2u(__builtin_amdgcn_cvt_pkrtz(wg[80 + t], 0.f));
  }
  if (t < 32) {
    wp[320 + t] = h2u(__builtin_amdgcn_cvt_pkrtz(wg[608 + t], 0.f));
    for (int j = 0; j < 8; j++)
      wp[48 + t * 8 + j] = h2u(__builtin_amdgcn_cvt_pkrtz(wg[96 + t * 16 + 2 * j],
                                                          wg[96 + t * 16 + 2 * j + 1]));
  }
}

__global__ void zero_kernel(int* __restrict__ p, int n) {
  int i = blockIdx.x * blockDim.x + threadIdx.x;
  if (i < n) p[i] = 0;
}

// per-block LDS histogram of dst buckets (bucket = dst>>7), flush to bucketCur
__global__ __launch_bounds__(1024) void bhist_kernel(const int* __restrict__ dst,
                                                     int* __restrict__ bucketCur,
                                                     int E, int NBUCK) {
  __shared__ int h[1024];
  int tid = threadIdx.x;
  for (int i = tid; i < NBUCK; i += 1024) h[i] = 0;
  __syncthreads();
  int base = blockIdx.x * 8192;
#pragma unroll
  for (int r = 0; r < 8; r++) {
    int e = base + r * 1024 + tid;
    if (e < E) atomicAdd(&h[dst[e] >> 7], 1);
  }
  __syncthreads();
  for (int i = tid; i < NBUCK; i += 1024) {
    int c = h[i];
    if (c) atomicAdd(&bucketCur[i], c);
  }
}

// single-block exclusive scan over NBUCK (<=1024) counts held in bucketCur;
// writes bucketOff[0..NBUCK] and re-seeds bucketCur with the exclusive offsets
__global__ __launch_bounds__(1024) void scanBk_kernel(int* __restrict__ bucketCur,
                                                      int* __restrict__ bucketOff,
                                                      int NBUCK) {
  __shared__ int wsum[16];
  __shared__ int woff[16];
  int tid = threadIdx.x, lane = tid & 63, wid = tid >> 6;
  int v = (tid < NBUCK) ? bucketCur[tid] : 0;
  int x = v;
#pragma unroll
  for (int off = 1; off < 64; off <<= 1) {
    int t = __shfl_up(x, off, 64);
    if (lane >= off) x += t;
  }
  if (lane == 63) wsum[wid] = x;
  __syncthreads();
  if (wid == 0) {
    int s = (lane < 16) ? wsum[lane] : 0;
#pragma unroll
    for (int off = 1; off < 16; off <<= 1) {
      int t = __shfl_up(s, off, 64);
      if (lane >= off) s += t;
    }
    if (lane < 16) woff[lane] = s - wsum[lane];
  }
  __syncthreads();
  int excl = woff[wid] + x - v;
  if (tid < NBUCK) {
    bucketOff[tid] = excl;
    bucketCur[tid] = excl;
    if (tid == NBUCK - 1) bucketOff[NBUCK] = excl + v;
  }
}

// partition edges into bucket regions: per-block LDS hist -> global reserve ->
// LDS-cursor append. Writes SoA (bsrc, bea, bdst) with ~NBUCK hot frontiers.
__global__ __launch_bounds__(1024) void part_kernel(
    const int* __restrict__ src, const int* __restrict__ dst,
    const float2* __restrict__ ea, int* __restrict__ bucketCur,
    int* __restrict__ bsrc, unsigned int* __restrict__ bea,
    int* __restrict__ bdst, int E, int NBUCK) {
  __shared__ int h[1024];
  int tid = threadIdx.x;
  for (int i = tid; i < NBUCK; i += 1024) h[i] = 0;
  __syncthreads();
  int base = blockIdx.x * 4096;
  int d[4], s[4];
  unsigned int a[4];
  bool v[4];
#pragma unroll
  for (int j = 0; j < 4; j++) {
    int e = base + j * 1024 + tid;
    v[j] = e < E;
    if (v[j]) {
      d[j] = dst[e];
      s[j] = src[e];
      float2 t = ea[e];
      a[j] = h2u(__builtin_amdgcn_cvt_pkrtz(t.x, t.y));
      atomicAdd(&h[d[j] >> 7], 1);
    }
  }
  __syncthreads();
  for (int i = tid; i < NBUCK; i += 1024) {
    int c = h[i];
    h[i] = c ? atomicAdd(&bucketCur[i], c) : 0;
  }
  __syncthreads();
#pragma unroll
  for (int j = 0; j < 4; j++) {
    if (v[j]) {
      int pos = atomicAdd(&h[d[j] >> 7], 1);
      bsrc[pos] = s[j];
      bdst[pos] = d[j];
      bea[pos] = a[j];
    }
  }
}

// per-bucket degree via LDS histogram; coalesced non-atomic deg write
__global__ __launch_bounds__(256) void deg_kernel(const int* __restrict__ bdst,
                                                  const int* __restrict__ bucketOff,
                                                  int* __restrict__ deg, int N) {
  __shared__ int cnt[128];
  int b = blockIdx.x, tid = threadIdx.x;
  if (tid < 128) cnt[tid] = 0;
  __syncthreads();
  int e0 = bucketOff[b], e1 = bucketOff[b + 1];
  for (int i = e0 + tid; i < e1; i += 256) atomicAdd(&cnt[bdst[i] & 127], 1);
  __syncthreads();
  int node = b * 128 + tid;
  if (tid < 128 && node < N) deg[node] = cnt[tid];
}

// ---- 3-phase exclusive scan over deg -> cursor (start positions) ----
__global__ void scanA_kernel(const int* __restrict__ deg, int* __restrict__ part, int n) {
  __shared__ int ws[16];
  int tid = threadIdx.x;
  int i = blockIdx.x * 1024 + tid;
  int v = (i < n) ? deg[i] : 0;
#pragma unroll
  for (int off = 32; off >= 1; off >>= 1) v += __shfl_down(v, off, 64);
  if ((tid & 63) == 0) ws[tid >> 6] = v;
  __syncthreads();
  if (tid == 0) {
    int s = 0;
#pragma unroll
    for (int k = 0; k < 16; k++) s += ws[k];
    part[blockIdx.x] = s;
  }
}

__global__ void scanB_kernel(int* __restrict__ part, int P) {
  int lane = threadIdx.x;
  int carry = 0;
  for (int base = 0; base < P; base += 64) {
    int i = base + lane;
    int v = (i < P) ? part[i] : 0;
    int x = v;
#pragma unroll
    for (int off = 1; off < 64; off <<= 1) {
      int t = __shfl_up(x, off, 64);
      if (lane >= off) x += t;
    }
    if (i < P) part[i] = carry + x - v;
    carry += __shfl(x, 63, 64);
  }
}

__global__ void scanC_kernel(const int* __restrict__ deg, const int* __restrict__ part,
                             int* __restrict__ cursor, int n) {
  __shared__ int wsum[16];
  __shared__ int woff[16];
  int tid = threadIdx.x, lane = tid & 63, wid = tid >> 6;
  int i = blockIdx.x * 1024 + tid;
  int v = (i < n) ? deg[i] : 0;
  int x = v;
#pragma unroll
  for (int off = 1; off < 64; off <<= 1) {
    int t = __shfl_up(x, off, 64);
    if (lane >= off) x += t;
  }
  if (lane == 63) wsum[wid] = x;
  __syncthreads();
  if (wid == 0) {
    int s = (lane < 16) ? wsum[lane] : 0;
#pragma unroll
    for (int off = 1; off < 16; off <<= 1) {
      int t = __shfl_up(s, off, 64);
      if (lane >= off) s += t;
    }
    if (lane < 16) woff[lane] = s - wsum[lane];
  }
  __syncthreads();
  if (i < n) cursor[i] = part[blockIdx.x] + woff[wid] + x - v;
}

// per-bucket final scatter: LDS cursors seeded from global start-cursor;
// writes AoS records into the bucket's contiguous (L2-hot) final region.
__global__ __launch_bounds__(256) void scat_kernel(
    const int* __restrict__ bsrc, const unsigned int* __restrict__ bea,
    const int* __restrict__ bdst, const int* __restrict__ bucketOff,
    const int* __restrict__ cursor, int4* __restrict__ erec, int N) {
  __shared__ int lcur[128];
  int b = blockIdx.x, tid = threadIdx.x;
  int node = b * 128 + tid;
  if (tid < 128) lcur[tid] = (node < N) ? cursor[node] : 0;
  __syncthreads();
  int e0 = bucketOff[b], e1 = bucketOff[b + 1];
  for (int i = e0 + tid; i < e1; i += 256) {
    int d = bdst[i];
    int pos = atomicAdd(&lcur[d & 127], 1);
    erec[pos] = make_int4(bsrc[i], d, (int)bea[i], 0);
  }
}

// pack x to fp16 pairs
__global__ void xpack_kernel(const float* __restrict__ x, uint2* __restrict__ xpk, int n) {
  int i = blockIdx.x * blockDim.x + threadIdx.x;
  if (i < n) {
    h2 a = __builtin_amdgcn_cvt_pkrtz(x[3 * i], x[3 * i + 1]);
    h2 b = __builtin_amdgcn_cvt_pkrtz(x[3 * i + 2], 0.f);
    xpk[i] = make_uint2(h2u(a), h2u(b));
  }
}

// ATOMIC-FREE edge kernel: window=64 edges/wave, NATIVE v_pk_fma_f16 MLP,
// wave segmented max, head lanes: complete run -> direct store; else partials.
__global__ __launch_bounds__(256) void edge_kernel(
    const uint2* __restrict__ xpk, const int4* __restrict__ erec,
    unsigned int* __restrict__ agg,
    int* __restrict__ pdstL, uint4* __restrict__ pvalL,
    int* __restrict__ pdstR, uint4* __restrict__ pvalR,
    const float* __restrict__ wg, int E) {
  const unsigned int* wp = (const unsigned int*)(wg + PKOFS);
  int e = blockIdx.x * 256 + threadIdx.x;
  int lane = threadIdx.x & 63;
  int w = e >> 6;
  int wbase = w << 6;
  bool vld = e < E;
  int4 rec = erec[vld ? e : (E - 1)];
  int d = vld ? rec.y : -1;
  uint2 xs = xpk[rec.x];

  // inputs as 3 fp16 pairs: (x0,x1), (x2,ea0), (ea1,0)
  h2 i0 = u2h(xs.x);
  unsigned int c0 = (xs.y & 0xffffu) | (((unsigned int)rec.z) << 16);
  unsigned int c1 = ((unsigned int)rec.z) >> 16;
  h2 i1 = u2h(c0), i2 = u2h(c1);

  // ---- layer 1 (pk_fma, fp16 accumulate, horizontal combine) ----
  unsigned int m1[8];
#pragma unroll
  for (int p = 0; p < 8; p++) {
    const int oA = 2 * p, oB = 2 * p + 1;
    h2 aA = pkfma(i0, u2h(wp[oA]),
             pkfma(i1, u2h(wp[16 + oA]),
              pkfma(i2, u2h(wp[32 + oA]), u2h(wp[304 + oA]))));
    h2 aB = pkfma(i0, u2h(wp[oB]),
             pkfma(i1, u2h(wp[16 + oB]),
              pkfma(i2, u2h(wp[32 + oB]), u2h(wp[304 + oB]))));
    m1[p] = umax2(combo(hsum(aB), hsum(aA)), 0u);  // relu, packed (out2p, out2p+1)
  }

  // ---- layer 2 (pk_fma over 8 k-pairs per output) ----
  unsigned int pk[16];
#pragma unroll
  for (int q = 0; q < 16; q++) {
    const int oA = 2 * q, oB = 2 * q + 1;
    h2 aA = u2h(wp[320 + oA]);
    h2 aB = u2h(wp[320 + oB]);
#pragma unroll
    for (int k = 0; k < 8; k++) {
      aA = pkfma(u2h(m1[k]), u2h(wp[48 + oA * 8 + k]), aA);
      aB = pkfma(u2h(m1[k]), u2h(wp[48 + oB * 8 + k]), aB);
    }
    pk[q] = umax2(combo(hsum(aB), hsum(aA)), 0u);
  }

  // ---- neighbor dsts across window boundaries ----
  int dp = -2, dn = -2;
  if (lane == 0 && wbase > 0) dp = erec[wbase - 1].y;
  if (lane == 63 && wbase + 64 < E) dn = erec[wbase + 64].y;
  dp = __shfl(dp, 0, 64);
  dn = __shfl(dn, 63, 64);

  // ---- wave segmented max (lane gets max from itself to segment end) ----
#pragma unroll
  for (int off = 1; off < 64; off <<= 1) {
    int d2 = __shfl_down(d, off, 64);
    unsigned int msk = ((lane + off < 64) && (d2 == d)) ? 0xFFFFFFFFu : 0u;
#pragma unroll
    for (int i = 0; i < 16; i++) {
      unsigned int v2 = __shfl_down(pk[i], off, 64) & msk;
      pk[i] = umax2(pk[i], v2);
    }
  }

  int dprev = __shfl_up(d, 1, 64);
  bool isHead = vld && (lane == 0 || d != dprev);
  unsigned long long hm = __ballot(isHead);
  if (isHead) {
    int lastHead = 63 - __builtin_clzll(hm);
    bool contL = (lane == 0) && (d == dp);
    bool contR = (lane == lastHead) && (d == dn);
    uint4 v0 = make_uint4(pk[0], pk[1], pk[2], pk[3]);
    uint4 v1 = make_uint4(pk[4], pk[5], pk[6], pk[7]);
    uint4 v2 = make_uint4(pk[8], pk[9], pk[10], pk[11]);
    uint4 v3 = make_uint4(pk[12], pk[13], pk[14], pk[15]);
    if (!contL && !contR) {
      uint4* a = (uint4*)(agg + (size_t)d * 16);
      a[0] = v0; a[1] = v1; a[2] = v2; a[3] = v3;
    } else if (contL) {
      pdstL[w] = d;
      pvalL[w * 4 + 0] = v0; pvalL[w * 4 + 1] = v1;
      pvalL[w * 4 + 2] = v2; pvalL[w * 4 + 3] = v3;
    } else {
      pdstR[w] = d;
      pvalR[w * 4 + 0] = v0; pvalR[w * 4 + 1] = v1;
      pvalR[w * 4 + 2] = v2; pvalR[w * 4 + 3] = v3;
    }
  }
}

__device__ __forceinline__ void max4(uint4& a, uint4 b) {
  a.x = umax2(a.x, b.x); a.y = umax2(a.y, b.y);
  a.z = umax2(a.z, b.z); a.w = umax2(a.w, b.w);
}

// node-parallel: reassemble aggregation, node MLP. cursor = START positions.
__global__ __launch_bounds__(256) void node_kernel(
    const float* __restrict__ x, const float* __restrict__ cin,
    float* __restrict__ cout, uint2* __restrict__ xpk,
    float* __restrict__ outFinal, const unsigned int* __restrict__ agg,
    const int* __restrict__ deg, const int* __restrict__ cursor,
    const int* __restrict__ pdstL, const uint4* __restrict__ pvalL,
    const int* __restrict__ pdstR, const uint4* __restrict__ pvalR,
    const float* __restrict__ wg, int n) {
  int nid = blockIdx.x * blockDim.x + threadIdx.x;
  if (nid >= n) return;
  int dg = deg[nid];
  uint4 q0 = make_uint4(0u, 0u, 0u, 0u), q1 = q0, q2 = q0, q3 = q0;
  if (dg > 0) {
    int r0 = cursor[nid];
    int r1 = r0 + dg;
    int w0 = r0 >> 6, w1 = (r1 - 1) >> 6;
    if (w0 == w1) {
      const uint4* a = (const uint4*)(agg + (size_t)nid * 16);
      q0 = a[0]; q1 = a[1]; q2 = a[2]; q3 = a[3];
    } else {
      if (pdstR[w0] == nid) {
        q0 = pvalR[w0 * 4 + 0]; q1 = pvalR[w0 * 4 + 1];
        q2 = pvalR[w0 * 4 + 2]; q3 = pvalR[w0 * 4 + 3];
      }
      for (int w = w0 + 1; w <= w1; w++) {
        if (pdstL[w] == nid) {
          max4(q0, pvalL[w * 4 + 0]); max4(q1, pvalL[w * 4 + 1]);
          max4(q2, pvalL[w * 4 + 2]); max4(q3, pvalL[w * 4 + 3]);
        }
      }
    }
  }
  unsigned int pkv[16] = {q0.x, q0.y, q0.z, q0.w, q1.x, q1.y, q1.z, q1.w,
                          q2.x, q2.y, q2.z, q2.w, q3.x, q3.y, q3.z, q3.w};
  float av[32];
#pragma unroll
  for (int i = 0; i < 16; i++) {
    h2 h = u2h(pkv[i]);
    av[2 * i] = (float)h.x;
    av[2 * i + 1] = (float)h.y;
  }
  float x0 = x[3 * nid], x1 = x[3 * nid + 1];
  float x2 = cin ? cin[nid] : x[3 * nid + 2];
  float h[16];
#pragma unroll
  for (int o = 0; o < 16; o++) {
    float sa = wg[1200 + o];
    sa = fmaf(wg[640 + o * 35 + 0], x0, sa);
    sa = fmaf(wg[640 + o * 35 + 1], x1, sa);
    sa = fmaf(wg[640 + o * 35 + 2], x2, sa);
#pragma unroll
    for (int k = 0; k < 32; k++) sa = fmaf(wg[640 + o * 35 + 3 + k], av[k], sa);
    h[o] = fmaxf(sa, 0.f);
  }
  float z = wg[1232];
#pragma unroll
  for (int k = 0; k < 16; k++) z = fmaf(wg[1216 + k], h[k], z);
  float comb = 1.f / (1.f + expf(-z));
  cout[nid] = comb;
  ((unsigned int*)xpk)[2 * nid + 1] = h2u(__builtin_amdgcn_cvt_pkrtz(comb, 0.f));
  if (outFinal) {
    outFinal[3 * nid] = x0;
    outFinal[3 * nid + 1] = x1;
    outFinal[3 * nid + 2] = comb;
  }
}

extern "C" void kernel_launch(void* const* d_in, const int* in_sizes, int n_in,
                              void* d_out, int out_size, void* d_ws, size_t ws_size,
                              hipStream_t stream) {
  const float* x = (const float*)d_in[0];
  const float* ea = (const float*)d_in[1];
  const int* eidx = (const int*)d_in[2];
  const int N = in_sizes[0] / 3;
  const int E = in_sizes[1] / 2;
  const int* src = eidx;
  const int* dst = eidx + E;
  const int P = (N + 1023) / 1024;
  const int NW = (E + 63) / 64;      // windows
  const int NBUCK = (N + 127) >> 7;  // dst buckets (<=1024 for N<=131072)

  // ---- workspace carve-up ----
  char* p = (char*)d_ws;
  size_t off = 0;
  auto alloc = [&](size_t bytes) -> char* {
    char* r = p + off;
    off = (off + bytes + 255) & ~(size_t)255;
    return r;
  };
  float* wbuf = (float*)alloc((size_t)(PKOFS + PKTOT) * 4);
  int* deg = (int*)alloc((size_t)N * 4);
  int* part = (int*)alloc((size_t)P * 4);
  int* cursor = (int*)alloc((size_t)N * 4);
  int* bucketOff = (int*)alloc(((size_t)NBUCK + 1) * 4);
  int* bucketCur = (int*)alloc((size_t)NBUCK * 4);
  int4* erec = (int4*)alloc((size_t)E * 16);
  // UNION region: build-phase SoA (bsrc|bea|bdst, 12B/edge) aliased with
  // run-phase arrays (agg, xpk, partials, bufA/B ~15MB < E*12B)
  char* uni = alloc((size_t)E * 12);
  int* bsrc = (int*)uni;
  unsigned int* bea = (unsigned int*)(uni + (size_t)E * 4);
  int* bdst = (int*)(uni + (size_t)E * 8);
  size_t uoff = 0;
  auto ualloc = [&](size_t bytes) -> char* {
    char* r = uni + uoff;
    uoff = (uoff + bytes + 255) & ~(size_t)255;
    return r;
  };
  unsigned int* agg = (unsigned int*)ualloc((size_t)N * 16 * 4);
  uint2* xpk = (uint2*)ualloc((size_t)N * 8);
  int* pdstL = (int*)ualloc((size_t)NW * 4);
  int* pdstR = (int*)ualloc((size_t)NW * 4);
  uint4* pvalL = (uint4*)ualloc((size_t)NW * 64);
  uint4* pvalR = (uint4*)ualloc((size_t)NW * 64);
  float* bufA = (float*)ualloc((size_t)N * 4);
  float* bufB = (float*)ualloc((size_t)N * 4);
  (void)ws_size;

  PrepArgs pa;
  for (int l = 0; l < 4; l++) {
    pa.wmu[l] = (const float*)d_in[3 + 6 * l + 0];
    pa.wrho[l] = (const float*)d_in[3 + 6 * l + 1];
    pa.bmu[l] = (const float*)d_in[3 + 6 * l + 2];
    pa.brho[l] = (const float*)d_in[3 + 6 * l + 3];
    pa.epsw[l] = (const float*)d_in[3 + 6 * l + 4];
    pa.epsb[l] = (const float*)d_in[3 + 6 * l + 5];
  }
  pa.out = wbuf;

  const int TB = 256;
  auto blocks = [&](int n) { return dim3((n + TB - 1) / TB); };

  prep_all_kernel<<<dim3(1), dim3(1024), 0, stream>>>(pa);
  zero_kernel<<<blocks(NBUCK), dim3(TB), 0, stream>>>(bucketCur, NBUCK);
  bhist_kernel<<<dim3((E + 8191) / 8192), dim3(1024), 0, stream>>>(dst, bucketCur, E, NBUCK);
  scanBk_kernel<<<dim3(1), dim3(1024), 0, stream>>>(bucketCur, bucketOff, NBUCK);
  part_kernel<<<dim3((E + 4095) / 4096), dim3(1024), 0, stream>>>(
      src, dst, (const float2*)ea, bucketCur, bsrc, bea, bdst, E, NBUCK);
  deg_kernel<<<dim3(NBUCK), dim3(TB), 0, stream>>>(bdst, bucketOff, deg, N);
  scanA_kernel<<<dim3(P), dim3(1024), 0, stream>>>(deg, part, N);
  scanB_kernel<<<dim3(1), dim3(64), 0, stream>>>(part, P);
  scanC_kernel<<<dim3(P), dim3(1024), 0, stream>>>(deg, part, cursor, N);
  scat_kernel<<<dim3(NBUCK), dim3(TB), 0, stream>>>(bsrc, bea, bdst, bucketOff, cursor,
                                                    erec, N);
  xpack_kernel<<<blocks(N), dim3(TB), 0, stream>>>(x, xpk, N);

  float* outp = (float*)d_out;
  int eb = (E + 255) / 256;
  // iter 1
  edge_kernel<<<dim3(eb), dim3(TB), 0, stream>>>(xpk, erec, agg, pdstL, pvalL, pdstR,
                                                 pvalR, wbuf, E);
  node_kernel<<<blocks(N), dim3(TB), 0, stream>>>(x, nullptr, bufA, xpk, nullptr, agg,
                                                  deg, cursor, pdstL, pvalL, pdstR,
                                                  pvalR, wbuf, N);
  // iter 2
  edge_kernel<<<dim3(eb), dim3(TB), 0, stream>>>(xpk, erec, agg, pdstL, pvalL, pdstR,
                                                 pvalR, wbuf, E);
  node_kernel<<<blocks(N), dim3(TB), 0, stream>>>(x, bufA, bufB, xpk, nullptr, agg,
                                                  deg, cursor, pdstL, pvalL, pdstR,
                                                  pvalR, wbuf, N);
  // iter 3
  edge_kernel<<<dim3(eb), dim3(TB), 0, stream>>>(xpk, erec, agg, pdstL, pvalL, pdstR,
                                                 pvalR, wbuf, E);
  node_kernel<<<blocks(N), dim3(TB), 0, stream>>>(x, bufB, bufA, xpk, outp, agg,
                                                  deg, cursor, pdstL, pvalL, pdstR,
                                                  pvalR, wbuf, N);
}